// Round 11
// baseline (488.140 us; speedup 1.0000x reference)
//
#include <hip/hip_runtime.h>
#include <hip/hip_bf16.h>

#define SEQL 2048
#define DMODEL 1024
#define NH 16
#define HEADP 64
#define FINALD 1024
#define REP 8   // measurement round: every kernel repeats its work 8x serially

using bf16x8 = __attribute__((ext_vector_type(8))) short;   // 8 bf16 (MFMA A/B frag)
using f32x4  = __attribute__((ext_vector_type(4))) float;   // MFMA C/D frag
using s16x4  = __attribute__((ext_vector_type(4))) short;   // 8B LDS write

// counted vmcnt wait: loads stay in flight across barriers (T4)
#define WAITV(N) asm volatile("s_waitcnt vmcnt(" #N ")" ::: "memory")

__device__ __forceinline__ f32x4 mfma16(bf16x8 a, bf16x8 b, f32x4 c) {
  return __builtin_amdgcn_mfma_f32_16x16x32_bf16(a, b, c, 0, 0, 0);
}

__device__ __forceinline__ unsigned short f2bf(float f) {
  return __builtin_bit_cast(unsigned short, __float2bfloat16(f));
}

// async global->LDS, 16B/lane; LDS dest = wave-uniform base + lane*16
__device__ __forceinline__ void gload16(const void* g, void* l) {
  __builtin_amdgcn_global_load_lds(
      (const __attribute__((address_space(1))) void*)g,
      (__attribute__((address_space(3))) void*)l, 16, 0, 0);
}

// ---- fused prep: weight transposes + x conversion in ONE launch ---------
__global__ __launch_bounds__(256) void k_prep(
    const float* __restrict__ Qw, const float* __restrict__ Kw,
    const float* __restrict__ Vw, const float* __restrict__ Wf,
    const float* __restrict__ x,
    unsigned short* __restrict__ Wt, unsigned short* __restrict__ WfT,
    unsigned short* __restrict__ xb) {
  __shared__ float tile[64][65];
  int z = blockIdx.z;
  int t = threadIdx.x;
  for (int rep = 0; rep < REP; ++rep) {
    if (z == 4) {                             // x conversion
      long i0 = ((long)blockIdx.y * 16 + blockIdx.x) * 2048 + t;
#pragma unroll
      for (int k = 0; k < 8; ++k) {
        long i = i0 + k * 256;
        float4 v = reinterpret_cast<const float4*>(x)[i];
        ushort4 o;
        o.x = f2bf(v.x); o.y = f2bf(v.y); o.z = f2bf(v.z); o.w = f2bf(v.w);
        reinterpret_cast<ushort4*>(xb)[i] = o;
      }
      continue;
    }
    const float* src; unsigned short* dst;
    int C, tr = blockIdx.x * 64, tc;
    if (z < 3) {
      const float* s3 = (z == 0) ? Qw : (z == 1) ? Kw : Vw;
      src = s3 + (long)blockIdx.y * 65536;                  // head slab [1024][64]
      dst = Wt + (long)z * 1048576 + (long)blockIdx.y * 65536;
      C = 64; tc = 0;
    } else {
      src = Wf; dst = WfT; C = 1024; tc = blockIdx.y * 64;
    }
    const int R = 1024;
    int r0 = t >> 4, c4 = (t & 15) * 4;
#pragma unroll
    for (int i = 0; i < 4; ++i) {
      int r = i * 16 + r0;
      float4 v = *reinterpret_cast<const float4*>(src + (long)(tr + r) * C + tc + c4);
      tile[r][c4 + 0] = v.x; tile[r][c4 + 1] = v.y;
      tile[r][c4 + 2] = v.z; tile[r][c4 + 3] = v.w;
    }
    __syncthreads();
    int r4 = (t & 15) * 4, cc0 = t >> 4;
#pragma unroll
    for (int i = 0; i < 4; ++i) {
      int c = i * 16 + cc0;
      ushort4 o;
      o.x = f2bf(tile[r4 + 0][c]); o.y = f2bf(tile[r4 + 1][c]);
      o.z = f2bf(tile[r4 + 2][c]); o.w = f2bf(tile[r4 + 3][c]);
      *reinterpret_cast<ushort4*>(dst + (long)(tc + c) * R + tr + r4) = o;
    }
    __syncthreads();   // tile reuse across reps
  }
}

// ---- unified LDS-staged GEMM, 128x64 tile, BK=64, counted-vmcnt --------
// (round-8 structure; REP-looped for measurement)
template <int EPI>
__global__ __launch_bounds__(256) void k_gemm(
    const unsigned short* __restrict__ A,    // [M][K] bf16
    const unsigned short* __restrict__ Bt,   // [N][K] bf16 (B^T)
    int K,
    unsigned short* __restrict__ Qb,         // [H][S][P]
    unsigned short* __restrict__ Kb,         // [H][S][P]
    unsigned short* __restrict__ Vtb,        // [H][P][S]
    const float* __restrict__ bias,
    float* __restrict__ outf) {              // [S][FINAL]
  __shared__ char lds[49152];
  int flat = blockIdx.y * 16 + blockIdx.x;
  int cpx = (gridDim.x * gridDim.y) >> 3;
  flat = (flat & 7) * cpx + (flat >> 3);     // XCD k owns contiguous chunk
  int m0 = (flat & 15) << 7, n0 = (flat >> 4) * 64;
  int t = threadIdx.x;
  int l = t & 63, w = t >> 6;
  int r = l & 15, g = l >> 4;
  int wr = w >> 1, wc = w & 1;

  const unsigned short* Arow = A + (long)m0 * K;
  const unsigned short* Brow = Bt + (long)n0 * K;
  int rr = l >> 2;
  int c8s = (((l & 3) ^ ((l >> 3) & 3)) * 8);

  auto stage = [&](int buf, int k0) {
    char* base = lds + buf * 24576;
#pragma unroll
    for (int kk = 0; kk < 2; ++kk) {
      char* dA = base + kk * 8192 + w * 2048;
      char* dB = base + 16384 + kk * 4096 + w * 1024;
      int kc = k0 + kk * 32 + c8s;
      gload16(Arow + (long)(w * 32 + rr) * K + kc, dA);
      gload16(Arow + (long)(w * 32 + 16 + rr) * K + kc, dA + 1024);
      gload16(Brow + (long)(w * 16 + rr) * K + kc, dB);
    }
  };

  int xk = (r >> 1) & 3;
  for (int rep = 0; rep < REP; ++rep) {
    f32x4 acc[4][2] = {};
    int cur = 0, NK = K / 64;
    stage(0, 0);                             // NK even: last iter reads buf1, safe
    for (int kt = 0; kt < NK; ++kt) {
      __builtin_amdgcn_s_barrier();          // A: all done reading buf cur^1
      if (kt + 1 < NK) {
        stage(cur ^ 1, (kt + 1) * 64);
        WAITV(6);
      } else {
        WAITV(0);
      }
      __builtin_amdgcn_s_barrier();          // B: everyone's cur loads landed
      __builtin_amdgcn_sched_barrier(0);
      const char* base = lds + cur * 24576;
#pragma unroll
      for (int kk = 0; kk < 2; ++kk) {
        const char* As = base + kk * 8192;
        const char* Bs = base + 16384 + kk * 4096;
        bf16x8 af[4], bb[2];
#pragma unroll
        for (int i = 0; i < 4; ++i)
          af[i] = *reinterpret_cast<const bf16x8*>(As + (wr * 64 + i * 16 + r) * 64 + ((g ^ xk) * 16));
#pragma unroll
        for (int i = 0; i < 2; ++i)
          bb[i] = *reinterpret_cast<const bf16x8*>(Bs + (wc * 32 + i * 16 + r) * 64 + ((g ^ xk) * 16));
#pragma unroll
        for (int mi = 0; mi < 4; ++mi)
#pragma unroll
          for (int ni = 0; ni < 2; ++ni)
            acc[mi][ni] = mfma16(af[mi], bb[ni], acc[mi][ni]);
      }
      cur ^= 1;
    }

    if constexpr (EPI == 0) {
      int which = n0 >> 10;
      int hb = (n0 & 1023) >> 6;
      if (which < 2) {
        unsigned short* dst = (which == 0 ? Qb : Kb) + (long)hb * SEQL * HEADP;
#pragma unroll
        for (int mi = 0; mi < 4; ++mi) {
          int s0 = m0 + wr * 64 + mi * 16 + g * 4;
#pragma unroll
          for (int ni = 0; ni < 2; ++ni) {
            int p = wc * 32 + ni * 16 + r;
#pragma unroll
            for (int v = 0; v < 4; ++v)
              dst[(long)(s0 + v) * HEADP + p] = f2bf(acc[mi][ni][v]);
          }
        }
      } else {
        unsigned short* dst = Vtb + (long)hb * HEADP * SEQL;
#pragma unroll
        for (int mi = 0; mi < 4; ++mi) {
          int s0 = m0 + wr * 64 + mi * 16 + g * 4;
#pragma unroll
          for (int ni = 0; ni < 2; ++ni) {
            int p = wc * 32 + ni * 16 + r;
            ushort4 pk;
            pk.x = f2bf(acc[mi][ni][0]); pk.y = f2bf(acc[mi][ni][1]);
            pk.z = f2bf(acc[mi][ni][2]); pk.w = f2bf(acc[mi][ni][3]);
            *reinterpret_cast<ushort4*>(dst + (long)p * SEQL + s0) = pk;
          }
        }
      }
    } else {
#pragma unroll
      for (int ni = 0; ni < 2; ++ni) {
        int c = n0 + wc * 32 + ni * 16 + r;
        float bv = bias[c];
#pragma unroll
        for (int mi = 0; mi < 4; ++mi) {
          int s0 = m0 + wr * 64 + mi * 16 + g * 4;
#pragma unroll
          for (int v = 0; v < 4; ++v)
            outf[(long)(s0 + v) * FINALD + c] = acc[mi][ni][v] + bv;
        }
      }
    }
  }
}

// ---- fused sigmoid attention: round-8 config (16 q/wave, 512 blocks) ---
// REP-looped for measurement.
__global__ __launch_bounds__(256) void k_attn(
    const unsigned short* __restrict__ Qb,   // [H][S][P]
    const unsigned short* __restrict__ Kb,   // [H][S][P]
    const unsigned short* __restrict__ Vtb,  // [H][P][S]
    unsigned short* __restrict__ Ab) {       // [H][S][P] bf16
  __shared__ char lds[40960];
  int b = blockIdx.x;
  int xcd = b & 7, j = b >> 3;
  int h = (xcd << 1) | (j & 1);   // heads {2*xcd, 2*xcd+1} pinned to xcd
  int sblk = j >> 1;              // 0..31
  int lane = threadIdx.x & 63, wave = threadIdx.x >> 6;
  int r = lane & 15, g = lane >> 4;
  int q0 = sblk * 64 + wave * 16;
  const unsigned short* Qh = Qb + ((long)h * SEQL + q0) * HEADP;
  const unsigned short* Kh = Kb + (long)h * SEQL * HEADP;
  const unsigned short* Vh = Vtb + (long)h * HEADP * SEQL;

  bf16x8 qf0 = *reinterpret_cast<const bf16x8*>(Qh + (long)r * HEADP + g * 8);
  bf16x8 qf1 = *reinterpret_cast<const bf16x8*>(Qh + (long)r * HEADP + 32 + g * 8);

  f32x4 z4 = {0.f, 0.f, 0.f, 0.f};
  char* slab = lds + 32768 + wave * 2048;
  int swz = (r & 7) << 4;
  const float CLN = -0.02254211001389005f;   // -log2(e)/64

  int sub = lane >> 3, chunk = lane & 7;
  auto stage = [&](int buf, int t0) {
    char* kb = lds + buf * 16384 + wave * 2048;
    char* vb = kb + 8192;
#pragma unroll
    for (int jj = 0; jj < 2; ++jj) {
      int row = wave * 16 + jj * 8 + sub;
      int sw = (chunk ^ (row & 7)) * 8;
      gload16(Kh + (long)(t0 + row) * HEADP + sw, kb + jj * 1024);
      gload16(Vh + (long)row * SEQL + t0 + sw, vb + jj * 1024);
    }
  };

  for (int rep = 0; rep < REP; ++rep) {
    f32x4 oacc[4] = {z4, z4, z4, z4};
    int cur = 0;
    stage(0, 0);                             // 32 iters even: last reads buf1, safe
    for (int t0 = 0; t0 < SEQL; t0 += 64) {
      __builtin_amdgcn_s_barrier();          // A: all done reading buf cur^1
      if (t0 + 64 < SEQL) {
        stage(cur ^ 1, t0 + 64);
        WAITV(4);
      } else {
        WAITV(0);
      }
      __builtin_amdgcn_s_barrier();          // B: everyone's cur loads landed
      __builtin_amdgcn_sched_barrier(0);

      const char* kb = lds + cur * 16384;
      const char* vb = kb + 8192;
      f32x4 s[4] = {z4, z4, z4, z4};
      __builtin_amdgcn_s_setprio(1);
#pragma unroll
      for (int tb = 0; tb < 4; ++tb) {
        const char* krow = kb + (tb * 16 + r) * 128;
        bf16x8 k0 = *reinterpret_cast<const bf16x8*>(krow + ((g ^ (r & 7)) * 16));
        bf16x8 k1 = *reinterpret_cast<const bf16x8*>(krow + (((4 + g) ^ (r & 7)) * 16));
        s[tb] = mfma16(k0, qf0, s[tb]);
        s[tb] = mfma16(k1, qf1, s[tb]);
      }
      __builtin_amdgcn_s_setprio(0);
#pragma unroll
      for (int tb = 0; tb < 4; ++tb) {
        s16x4 pk;
#pragma unroll
        for (int v = 0; v < 4; ++v) {
          float e = __builtin_amdgcn_exp2f(s[tb][v] * CLN);
          pk[v] = (short)f2bf(__builtin_amdgcn_rcpf(1.0f + e));
        }
        *reinterpret_cast<s16x4*>(slab + r * 128 + ((tb * 32 + g * 8) ^ swz)) = pk;
      }
      bf16x8 pa0 = *reinterpret_cast<const bf16x8*>(slab + r * 128 + ((g * 16) ^ swz));
      bf16x8 pa1 = *reinterpret_cast<const bf16x8*>(slab + r * 128 + ((64 + g * 16) ^ swz));
      __builtin_amdgcn_s_setprio(1);
#pragma unroll
      for (int nb = 0; nb < 4; ++nb) {
        const char* vrow = vb + (nb * 16 + r) * 128;
        bf16x8 v0 = *reinterpret_cast<const bf16x8*>(vrow + ((g ^ (r & 7)) * 16));
        bf16x8 v1 = *reinterpret_cast<const bf16x8*>(vrow + (((4 + g) ^ (r & 7)) * 16));
        oacc[nb] = mfma16(pa0, v0, oacc[nb]);
        oacc[nb] = mfma16(pa1, v1, oacc[nb]);
      }
      __builtin_amdgcn_s_setprio(0);
      cur ^= 1;
    }
    unsigned short* Oh = Ab + ((long)h * SEQL + q0) * HEADP;
#pragma unroll
    for (int nb = 0; nb < 4; ++nb)
#pragma unroll
      for (int v = 0; v < 4; ++v)
        Oh[(g * 4 + v) * HEADP + nb * 16 + r] = f2bf(oacc[nb][v]);
  }
}

// ---- launch -------------------------------------------------------------
extern "C" void kernel_launch(void* const* d_in, const int* in_sizes, int n_in,
                              void* d_out, int out_size, void* d_ws, size_t ws_size,
                              hipStream_t stream) {
  const float* x  = (const float*)d_in[0];
  const float* Qw = (const float*)d_in[1];
  const float* Kw = (const float*)d_in[2];
  const float* Vw = (const float*)d_in[3];
  const float* Wf = (const float*)d_in[4];
  const float* bf = (const float*)d_in[5];
  float* out = (float*)d_out;

  unsigned short* ws  = (unsigned short*)d_ws;
  unsigned short* xb  = ws;                // [2048][1024]       bytes [0,4M)
  unsigned short* Wt  = ws + 2097152;      // [3][16][64][1024]  bytes [4M,10M)
  unsigned short* WfT = ws + 5242880;      // [1024][1024]       bytes [10M,12M)
  unsigned short* Qb  = ws + 6291456;      // [16][2048][64]     bytes [12M,16M)
  unsigned short* Kb  = ws + 8388608;      //                    bytes [16M,20M)
  unsigned short* Vtb = ws + 10485760;     // [16][64][2048]     bytes [20M,24M)
  unsigned short* Ab  = ws + 12582912;     // [16][2048][64]     bytes [24M,28M)

  k_prep<<<dim3(16, 16, 5), 256, 0, stream>>>(Qw, Kw, Vw, Wf, x, Wt, WfT, xb);
  k_gemm<0><<<dim3(16, 48), 256, 0, stream>>>(xb, Wt, DMODEL, Qb, Kb, Vtb, nullptr, nullptr);
  k_attn<<<512, 256, 0, stream>>>(Qb, Kb, Vtb, Ab);
  k_gemm<1><<<dim3(16, 16), 256, 0, stream>>>(Ab, WfT, DMODEL, nullptr, nullptr, nullptr, bf, out);
}

// Round 12
// 80.891 us; speedup vs baseline: 6.0345x; 6.0345x over previous
//
#include <hip/hip_runtime.h>
#include <hip/hip_bf16.h>

#define SEQL 2048
#define DMODEL 1024
#define NH 16
#define HEADP 64
#define FINALD 1024

using bf16x8 = __attribute__((ext_vector_type(8))) short;   // 8 bf16 (MFMA A/B frag)
using f32x4  = __attribute__((ext_vector_type(4))) float;   // MFMA C/D frag
using s16x4  = __attribute__((ext_vector_type(4))) short;   // 8B LDS write

// counted vmcnt wait: loads stay in flight across barriers (T4)
#define WAITV(N) asm volatile("s_waitcnt vmcnt(" #N ")" ::: "memory")

__device__ __forceinline__ f32x4 mfma16(bf16x8 a, bf16x8 b, f32x4 c) {
  return __builtin_amdgcn_mfma_f32_16x16x32_bf16(a, b, c, 0, 0, 0);
}

__device__ __forceinline__ unsigned short f2bf(float f) {
  return __builtin_bit_cast(unsigned short, __float2bfloat16(f));
}

// async global->LDS, 16B/lane; LDS dest = wave-uniform base + lane*16
__device__ __forceinline__ void gload16(const void* g, void* l) {
  __builtin_amdgcn_global_load_lds(
      (const __attribute__((address_space(1))) void*)g,
      (__attribute__((address_space(3))) void*)l, 16, 0, 0);
}

// ---- fused prep: weight transposes + x conversion in ONE launch ---------
__global__ __launch_bounds__(256) void k_prep(
    const float* __restrict__ Qw, const float* __restrict__ Kw,
    const float* __restrict__ Vw, const float* __restrict__ Wf,
    const float* __restrict__ x,
    unsigned short* __restrict__ Wt, unsigned short* __restrict__ WfT,
    unsigned short* __restrict__ xb) {
  __shared__ float tile[64][65];
  int z = blockIdx.z;
  int t = threadIdx.x;
  if (z == 4) {                               // x conversion
    long i0 = ((long)blockIdx.y * 16 + blockIdx.x) * 2048 + t;
#pragma unroll
    for (int k = 0; k < 8; ++k) {
      long i = i0 + k * 256;
      float4 v = reinterpret_cast<const float4*>(x)[i];
      ushort4 o;
      o.x = f2bf(v.x); o.y = f2bf(v.y); o.z = f2bf(v.z); o.w = f2bf(v.w);
      reinterpret_cast<ushort4*>(xb)[i] = o;
    }
    return;
  }
  const float* src; unsigned short* dst;
  int C, tr = blockIdx.x * 64, tc;
  if (z < 3) {
    const float* s3 = (z == 0) ? Qw : (z == 1) ? Kw : Vw;
    src = s3 + (long)blockIdx.y * 65536;                  // head slab [1024][64]
    dst = Wt + (long)z * 1048576 + (long)blockIdx.y * 65536;
    C = 64; tc = 0;
  } else {
    src = Wf; dst = WfT; C = 1024; tc = blockIdx.y * 64;
  }
  const int R = 1024;
  int r0 = t >> 4, c4 = (t & 15) * 4;
#pragma unroll
  for (int i = 0; i < 4; ++i) {
    int r = i * 16 + r0;
    float4 v = *reinterpret_cast<const float4*>(src + (long)(tr + r) * C + tc + c4);
    tile[r][c4 + 0] = v.x; tile[r][c4 + 1] = v.y;
    tile[r][c4 + 2] = v.z; tile[r][c4 + 3] = v.w;
  }
  __syncthreads();
  int r4 = (t & 15) * 4, cc0 = t >> 4;
#pragma unroll
  for (int i = 0; i < 4; ++i) {
    int c = i * 16 + cc0;
    ushort4 o;
    o.x = f2bf(tile[r4 + 0][c]); o.y = f2bf(tile[r4 + 1][c]);
    o.z = f2bf(tile[r4 + 2][c]); o.w = f2bf(tile[r4 + 3][c]);
    *reinterpret_cast<ushort4*>(dst + (long)(tc + c) * R + tr + r4) = o;
  }
}

// ---- unified LDS-staged GEMM, 128x64 tile, BK=64, counted-vmcnt --------
// (round-8 structure)
template <int EPI>
__global__ __launch_bounds__(256) void k_gemm(
    const unsigned short* __restrict__ A,    // [M][K] bf16
    const unsigned short* __restrict__ Bt,   // [N][K] bf16 (B^T)
    int K,
    unsigned short* __restrict__ Qb,         // [H][S][P]
    unsigned short* __restrict__ Kb,         // [H][S][P]
    unsigned short* __restrict__ Vtb,        // [H][P][S]
    const float* __restrict__ bias,
    float* __restrict__ outf) {              // [S][FINAL]
  __shared__ char lds[49152];
  int flat = blockIdx.y * 16 + blockIdx.x;
  int cpx = (gridDim.x * gridDim.y) >> 3;
  flat = (flat & 7) * cpx + (flat >> 3);     // XCD k owns contiguous chunk
  int m0 = (flat & 15) << 7, n0 = (flat >> 4) * 64;
  int t = threadIdx.x;
  int l = t & 63, w = t >> 6;
  int r = l & 15, g = l >> 4;
  int wr = w >> 1, wc = w & 1;

  const unsigned short* Arow = A + (long)m0 * K;
  const unsigned short* Brow = Bt + (long)n0 * K;
  int rr = l >> 2;
  int c8s = (((l & 3) ^ ((l >> 3) & 3)) * 8);

  auto stage = [&](int buf, int k0) {
    char* base = lds + buf * 24576;
#pragma unroll
    for (int kk = 0; kk < 2; ++kk) {
      char* dA = base + kk * 8192 + w * 2048;
      char* dB = base + 16384 + kk * 4096 + w * 1024;
      int kc = k0 + kk * 32 + c8s;
      gload16(Arow + (long)(w * 32 + rr) * K + kc, dA);
      gload16(Arow + (long)(w * 32 + 16 + rr) * K + kc, dA + 1024);
      gload16(Brow + (long)(w * 16 + rr) * K + kc, dB);
    }
  };

  int xk = (r >> 1) & 3;
  f32x4 acc[4][2] = {};
  int cur = 0, NK = K / 64;
  stage(0, 0);
  for (int kt = 0; kt < NK; ++kt) {
    __builtin_amdgcn_s_barrier();            // A: all done reading buf cur^1
    if (kt + 1 < NK) {
      stage(cur ^ 1, (kt + 1) * 64);
      WAITV(6);
    } else {
      WAITV(0);
    }
    __builtin_amdgcn_s_barrier();            // B: everyone's cur loads landed
    __builtin_amdgcn_sched_barrier(0);
    const char* base = lds + cur * 24576;
#pragma unroll
    for (int kk = 0; kk < 2; ++kk) {
      const char* As = base + kk * 8192;
      const char* Bs = base + 16384 + kk * 4096;
      bf16x8 af[4], bb[2];
#pragma unroll
      for (int i = 0; i < 4; ++i)
        af[i] = *reinterpret_cast<const bf16x8*>(As + (wr * 64 + i * 16 + r) * 64 + ((g ^ xk) * 16));
#pragma unroll
      for (int i = 0; i < 2; ++i)
        bb[i] = *reinterpret_cast<const bf16x8*>(Bs + (wc * 32 + i * 16 + r) * 64 + ((g ^ xk) * 16));
#pragma unroll
      for (int mi = 0; mi < 4; ++mi)
#pragma unroll
        for (int ni = 0; ni < 2; ++ni)
          acc[mi][ni] = mfma16(af[mi], bb[ni], acc[mi][ni]);
    }
    cur ^= 1;
  }

  if constexpr (EPI == 0) {
    int which = n0 >> 10;
    int hb = (n0 & 1023) >> 6;
    if (which < 2) {
      unsigned short* dst = (which == 0 ? Qb : Kb) + (long)hb * SEQL * HEADP;
#pragma unroll
      for (int mi = 0; mi < 4; ++mi) {
        int s0 = m0 + wr * 64 + mi * 16 + g * 4;
#pragma unroll
        for (int ni = 0; ni < 2; ++ni) {
          int p = wc * 32 + ni * 16 + r;
#pragma unroll
          for (int v = 0; v < 4; ++v)
            dst[(long)(s0 + v) * HEADP + p] = f2bf(acc[mi][ni][v]);
        }
      }
    } else {
      unsigned short* dst = Vtb + (long)hb * HEADP * SEQL;
#pragma unroll
      for (int mi = 0; mi < 4; ++mi) {
        int s0 = m0 + wr * 64 + mi * 16 + g * 4;
#pragma unroll
        for (int ni = 0; ni < 2; ++ni) {
          int p = wc * 32 + ni * 16 + r;
          ushort4 pk;
          pk.x = f2bf(acc[mi][ni][0]); pk.y = f2bf(acc[mi][ni][1]);
          pk.z = f2bf(acc[mi][ni][2]); pk.w = f2bf(acc[mi][ni][3]);
          *reinterpret_cast<ushort4*>(dst + (long)p * SEQL + s0) = pk;
        }
      }
    }
  } else {
#pragma unroll
    for (int ni = 0; ni < 2; ++ni) {
      int c = n0 + wc * 32 + ni * 16 + r;
      float bv = bias[c];
#pragma unroll
      for (int mi = 0; mi < 4; ++mi) {
        int s0 = m0 + wr * 64 + mi * 16 + g * 4;
#pragma unroll
        for (int v = 0; v < 4; ++v)
          outf[(long)(s0 + v) * FINALD + c] = acc[mi][ni][v] + bv;
      }
    }
  }
}

// ---- fused sigmoid attention: t-split 2-way for phase interleave -------
// grid 1024 (4 blocks/CU = 16 waves/CU), block 256 (4 waves x 16 q-rows).
// Round-8 inner structure (counted-vmcnt dbuf staging, swizzles, setprio).
// f32 partials: tc=0 -> P0 (=d_out), tc=1 -> P1 (dead xb/Wt region).
__global__ __launch_bounds__(256) void k_attn(
    const unsigned short* __restrict__ Qb,   // [H][S][P]
    const unsigned short* __restrict__ Kb,   // [H][S][P]
    const unsigned short* __restrict__ Vtb,  // [H][P][S]
    float* __restrict__ P0, float* __restrict__ P1) {
  __shared__ char lds[40960];
  int b = blockIdx.x;
  int xcd = b & 7, j = b >> 3;               // j 0..127
  int h = (xcd << 1) | (j & 1);              // heads {2*xcd, 2*xcd+1} on xcd
  int sblk = (j >> 1) & 31;                  // 0..31
  int tc = j >> 6;                           // 0..1
  int lane = threadIdx.x & 63, wave = threadIdx.x >> 6;
  int r = lane & 15, g = lane >> 4;
  int q0 = sblk * 64 + wave * 16;
  const unsigned short* Qh = Qb + ((long)h * SEQL + q0) * HEADP;
  const unsigned short* Kh = Kb + (long)h * SEQL * HEADP;
  const unsigned short* Vh = Vtb + (long)h * HEADP * SEQL;

  bf16x8 qf0 = *reinterpret_cast<const bf16x8*>(Qh + (long)r * HEADP + g * 8);
  bf16x8 qf1 = *reinterpret_cast<const bf16x8*>(Qh + (long)r * HEADP + 32 + g * 8);

  f32x4 z4 = {0.f, 0.f, 0.f, 0.f};
  f32x4 oacc[4] = {z4, z4, z4, z4};
  char* slab = lds + 32768 + wave * 2048;
  int swz = (r & 7) << 4;
  const float CLN = -0.02254211001389005f;   // -log2(e)/64

  int sub = lane >> 3, chunk = lane & 7;
  auto stage = [&](int buf, int t0) {
    char* kb = lds + buf * 16384 + wave * 2048;
    char* vb = kb + 8192;
#pragma unroll
    for (int jj = 0; jj < 2; ++jj) {
      int row = wave * 16 + jj * 8 + sub;
      int sw = (chunk ^ (row & 7)) * 8;
      gload16(Kh + (long)(t0 + row) * HEADP + sw, kb + jj * 1024);
      gload16(Vh + (long)row * SEQL + t0 + sw, vb + jj * 1024);
    }
  };

  int tbeg = tc * (SEQL / 2), tend = tbeg + SEQL / 2;
  int cur = 0;
  stage(0, tbeg);                            // 4 loads in flight
  for (int t0 = tbeg; t0 < tend; t0 += 64) {
    __builtin_amdgcn_s_barrier();            // A: all done reading buf cur^1
    if (t0 + 64 < tend) {
      stage(cur ^ 1, t0 + 64);               // 4 more loads (8 outstanding)
      WAITV(4);                              // cur's loads landed
    } else {
      WAITV(0);
    }
    __builtin_amdgcn_s_barrier();            // B: everyone's cur loads landed
    __builtin_amdgcn_sched_barrier(0);

    const char* kb = lds + cur * 16384;
    const char* vb = kb + 8192;
    // S^T = K @ Q^T : lane holds S[t=tb*16+g*4+v][q=r]
    f32x4 s[4] = {z4, z4, z4, z4};
    __builtin_amdgcn_s_setprio(1);
#pragma unroll
    for (int tb = 0; tb < 4; ++tb) {
      const char* krow = kb + (tb * 16 + r) * 128;
      bf16x8 k0 = *reinterpret_cast<const bf16x8*>(krow + ((g ^ (r & 7)) * 16));
      bf16x8 k1 = *reinterpret_cast<const bf16x8*>(krow + (((4 + g) ^ (r & 7)) * 16));
      s[tb] = mfma16(k0, qf0, s[tb]);
      s[tb] = mfma16(k1, qf1, s[tb]);
    }
    __builtin_amdgcn_s_setprio(0);
    // sigmoid(S/64) -> bf16 -> per-wave slab (8B writes, swizzled)
#pragma unroll
    for (int tb = 0; tb < 4; ++tb) {
      s16x4 pk;
#pragma unroll
      for (int v = 0; v < 4; ++v) {
        float e = __builtin_amdgcn_exp2f(s[tb][v] * CLN);
        pk[v] = (short)f2bf(__builtin_amdgcn_rcpf(1.0f + e));
      }
      *reinterpret_cast<s16x4*>(slab + r * 128 + ((tb * 32 + g * 8) ^ swz)) = pk;
    }
    // PV: A-frags from slab, B-frags from V tile in LDS
    bf16x8 pa0 = *reinterpret_cast<const bf16x8*>(slab + r * 128 + ((g * 16) ^ swz));
    bf16x8 pa1 = *reinterpret_cast<const bf16x8*>(slab + r * 128 + ((64 + g * 16) ^ swz));
    __builtin_amdgcn_s_setprio(1);
#pragma unroll
    for (int nb = 0; nb < 4; ++nb) {
      const char* vrow = vb + (nb * 16 + r) * 128;
      bf16x8 v0 = *reinterpret_cast<const bf16x8*>(vrow + ((g ^ (r & 7)) * 16));
      bf16x8 v1 = *reinterpret_cast<const bf16x8*>(vrow + (((4 + g) ^ (r & 7)) * 16));
      oacc[nb] = mfma16(pa0, v0, oacc[nb]);
      oacc[nb] = mfma16(pa1, v1, oacc[nb]);
    }
    __builtin_amdgcn_s_setprio(0);
    cur ^= 1;
  }
  float* Po = (tc ? P1 : P0) + ((long)h * SEQL + q0) * HEADP;
#pragma unroll
  for (int nb = 0; nb < 4; ++nb)
#pragma unroll
    for (int v = 0; v < 4; ++v)
      Po[(g * 4 + v) * HEADP + nb * 16 + r] = oacc[nb][v];
}

// ---- reduce partials -> bf16 attn --------------------------------------
__global__ void k_reduce(const float* __restrict__ P0, const float* __restrict__ P1,
                         unsigned short* __restrict__ Ab, int n4) {
  int i = blockIdx.x * blockDim.x + threadIdx.x;
  if (i >= n4) return;
  float4 a = reinterpret_cast<const float4*>(P0)[i];
  float4 b = reinterpret_cast<const float4*>(P1)[i];
  ushort4 o;
  o.x = f2bf(a.x + b.x); o.y = f2bf(a.y + b.y);
  o.z = f2bf(a.z + b.z); o.w = f2bf(a.w + b.w);
  reinterpret_cast<ushort4*>(Ab)[i] = o;
}

// ---- launch -------------------------------------------------------------
extern "C" void kernel_launch(void* const* d_in, const int* in_sizes, int n_in,
                              void* d_out, int out_size, void* d_ws, size_t ws_size,
                              hipStream_t stream) {
  const float* x  = (const float*)d_in[0];
  const float* Qw = (const float*)d_in[1];
  const float* Kw = (const float*)d_in[2];
  const float* Vw = (const float*)d_in[3];
  const float* Wf = (const float*)d_in[4];
  const float* bf = (const float*)d_in[5];
  float* out = (float*)d_out;

  unsigned short* ws  = (unsigned short*)d_ws;
  unsigned short* xb  = ws;                // [2048][1024]       bytes [0,4M)
  unsigned short* Wt  = ws + 2097152;      // [3][16][64][1024]  bytes [4M,10M)
  unsigned short* WfT = ws + 5242880;      // [1024][1024]       bytes [10M,12M)
  unsigned short* Qb  = ws + 6291456;      // [16][2048][64]     bytes [12M,16M)
  unsigned short* Kb  = ws + 8388608;      //                    bytes [16M,20M)
  unsigned short* Vtb = ws + 10485760;     // [16][64][2048]     bytes [20M,24M)
  unsigned short* Ab  = ws + 12582912;     // [16][2048][64]     bytes [24M,28M)
  float* P0 = (float*)d_out;               // partial 0: d_out as scratch (8MB)
  float* P1 = (float*)d_ws;                // partial 1: overlays dead xb/Wt (8MB)

  k_prep<<<dim3(16, 16, 5), 256, 0, stream>>>(Qw, Kw, Vw, Wf, x, Wt, WfT, xb);
  k_gemm<0><<<dim3(16, 48), 256, 0, stream>>>(xb, Wt, DMODEL, Qb, Kb, Vtb, nullptr, nullptr);
  k_attn<<<1024, 256, 0, stream>>>(Qb, Kb, Vtb, P0, P1);
  k_reduce<<<2048, 256, 0, stream>>>(P0, P1, Ab, 524288);
  k_gemm<1><<<dim3(16, 16), 256, 0, stream>>>(Ab, WfT, DMODEL, nullptr, nullptr, nullptr, bf, out);
}

// Round 13
// 76.508 us; speedup vs baseline: 6.3802x; 1.0573x over previous
//
#include <hip/hip_runtime.h>
#include <hip/hip_bf16.h>

#define SEQL 2048
#define DMODEL 1024
#define NH 16
#define HEADP 64
#define FINALD 1024

using bf16x8 = __attribute__((ext_vector_type(8))) short;   // 8 bf16 (MFMA A/B frag)
using f32x4  = __attribute__((ext_vector_type(4))) float;   // MFMA C/D frag
using s16x4  = __attribute__((ext_vector_type(4))) short;   // 8B LDS write

// counted vmcnt wait: loads stay in flight across barriers (T4)
#define WAITV(N) asm volatile("s_waitcnt vmcnt(" #N ")" ::: "memory")

__device__ __forceinline__ f32x4 mfma16(bf16x8 a, bf16x8 b, f32x4 c) {
  return __builtin_amdgcn_mfma_f32_16x16x32_bf16(a, b, c, 0, 0, 0);
}

__device__ __forceinline__ unsigned short f2bf(float f) {
  return __builtin_bit_cast(unsigned short, __float2bfloat16(f));
}

// async global->LDS, 16B/lane; LDS dest = wave-uniform base + lane*16
__device__ __forceinline__ void gload16(const void* g, void* l) {
  __builtin_amdgcn_global_load_lds(
      (const __attribute__((address_space(1))) void*)g,
      (__attribute__((address_space(3))) void*)l, 16, 0, 0);
}

// ---- fused prep: weight transposes + x conversion in ONE launch ---------
__global__ __launch_bounds__(256) void k_prep(
    const float* __restrict__ Qw, const float* __restrict__ Kw,
    const float* __restrict__ Vw, const float* __restrict__ Wf,
    const float* __restrict__ x,
    unsigned short* __restrict__ Wt, unsigned short* __restrict__ WfT,
    unsigned short* __restrict__ xb) {
  __shared__ float tile[64][65];
  int z = blockIdx.z;
  int t = threadIdx.x;
  if (z == 4) {                               // x conversion
    long i0 = ((long)blockIdx.y * 16 + blockIdx.x) * 2048 + t;
#pragma unroll
    for (int k = 0; k < 8; ++k) {
      long i = i0 + k * 256;
      float4 v = reinterpret_cast<const float4*>(x)[i];
      ushort4 o;
      o.x = f2bf(v.x); o.y = f2bf(v.y); o.z = f2bf(v.z); o.w = f2bf(v.w);
      reinterpret_cast<ushort4*>(xb)[i] = o;
    }
    return;
  }
  const float* src; unsigned short* dst;
  int C, tr = blockIdx.x * 64, tc;
  if (z < 3) {
    const float* s3 = (z == 0) ? Qw : (z == 1) ? Kw : Vw;
    src = s3 + (long)blockIdx.y * 65536;                  // head slab [1024][64]
    dst = Wt + (long)z * 1048576 + (long)blockIdx.y * 65536;
    C = 64; tc = 0;
  } else {
    src = Wf; dst = WfT; C = 1024; tc = blockIdx.y * 64;
  }
  const int R = 1024;
  int r0 = t >> 4, c4 = (t & 15) * 4;
#pragma unroll
  for (int i = 0; i < 4; ++i) {
    int r = i * 16 + r0;
    float4 v = *reinterpret_cast<const float4*>(src + (long)(tr + r) * C + tc + c4);
    tile[r][c4 + 0] = v.x; tile[r][c4 + 1] = v.y;
    tile[r][c4 + 2] = v.z; tile[r][c4 + 3] = v.w;
  }
  __syncthreads();
  int r4 = (t & 15) * 4, cc0 = t >> 4;
#pragma unroll
  for (int i = 0; i < 4; ++i) {
    int c = i * 16 + cc0;
    ushort4 o;
    o.x = f2bf(tile[r4 + 0][c]); o.y = f2bf(tile[r4 + 1][c]);
    o.z = f2bf(tile[r4 + 2][c]); o.w = f2bf(tile[r4 + 3][c]);
    *reinterpret_cast<ushort4*>(dst + (long)(tc + c) * R + tr + r4) = o;
  }
}

// ---- unified LDS-staged GEMM, 128x64 tile, BK=64, counted-vmcnt --------
// (round-8 structure)
template <int EPI>
__global__ __launch_bounds__(256) void k_gemm(
    const unsigned short* __restrict__ A,    // [M][K] bf16
    const unsigned short* __restrict__ Bt,   // [N][K] bf16 (B^T)
    int K,
    unsigned short* __restrict__ Qb,         // [H][S][P]
    unsigned short* __restrict__ Kb,         // [H][S][P]
    unsigned short* __restrict__ Vtb,        // [H][P][S]
    const float* __restrict__ bias,
    float* __restrict__ outf) {              // [S][FINAL]
  __shared__ char lds[49152];
  int flat = blockIdx.y * 16 + blockIdx.x;
  int cpx = (gridDim.x * gridDim.y) >> 3;
  flat = (flat & 7) * cpx + (flat >> 3);     // XCD k owns contiguous chunk
  int m0 = (flat & 15) << 7, n0 = (flat >> 4) * 64;
  int t = threadIdx.x;
  int l = t & 63, w = t >> 6;
  int r = l & 15, g = l >> 4;
  int wr = w >> 1, wc = w & 1;

  const unsigned short* Arow = A + (long)m0 * K;
  const unsigned short* Brow = Bt + (long)n0 * K;
  int rr = l >> 2;
  int c8s = (((l & 3) ^ ((l >> 3) & 3)) * 8);

  auto stage = [&](int buf, int k0) {
    char* base = lds + buf * 24576;
#pragma unroll
    for (int kk = 0; kk < 2; ++kk) {
      char* dA = base + kk * 8192 + w * 2048;
      char* dB = base + 16384 + kk * 4096 + w * 1024;
      int kc = k0 + kk * 32 + c8s;
      gload16(Arow + (long)(w * 32 + rr) * K + kc, dA);
      gload16(Arow + (long)(w * 32 + 16 + rr) * K + kc, dA + 1024);
      gload16(Brow + (long)(w * 16 + rr) * K + kc, dB);
    }
  };

  int xk = (r >> 1) & 3;
  f32x4 acc[4][2] = {};
  int cur = 0, NK = K / 64;
  stage(0, 0);
  for (int kt = 0; kt < NK; ++kt) {
    __builtin_amdgcn_s_barrier();            // A: all done reading buf cur^1
    if (kt + 1 < NK) {
      stage(cur ^ 1, (kt + 1) * 64);
      WAITV(6);
    } else {
      WAITV(0);
    }
    __builtin_amdgcn_s_barrier();            // B: everyone's cur loads landed
    __builtin_amdgcn_sched_barrier(0);
    const char* base = lds + cur * 24576;
#pragma unroll
    for (int kk = 0; kk < 2; ++kk) {
      const char* As = base + kk * 8192;
      const char* Bs = base + 16384 + kk * 4096;
      bf16x8 af[4], bb[2];
#pragma unroll
      for (int i = 0; i < 4; ++i)
        af[i] = *reinterpret_cast<const bf16x8*>(As + (wr * 64 + i * 16 + r) * 64 + ((g ^ xk) * 16));
#pragma unroll
      for (int i = 0; i < 2; ++i)
        bb[i] = *reinterpret_cast<const bf16x8*>(Bs + (wc * 32 + i * 16 + r) * 64 + ((g ^ xk) * 16));
#pragma unroll
      for (int mi = 0; mi < 4; ++mi)
#pragma unroll
        for (int ni = 0; ni < 2; ++ni)
          acc[mi][ni] = mfma16(af[mi], bb[ni], acc[mi][ni]);
    }
    cur ^= 1;
  }

  if constexpr (EPI == 0) {
    int which = n0 >> 10;
    int hb = (n0 & 1023) >> 6;
    if (which < 2) {
      unsigned short* dst = (which == 0 ? Qb : Kb) + (long)hb * SEQL * HEADP;
#pragma unroll
      for (int mi = 0; mi < 4; ++mi) {
        int s0 = m0 + wr * 64 + mi * 16 + g * 4;
#pragma unroll
        for (int ni = 0; ni < 2; ++ni) {
          int p = wc * 32 + ni * 16 + r;
#pragma unroll
          for (int v = 0; v < 4; ++v)
            dst[(long)(s0 + v) * HEADP + p] = f2bf(acc[mi][ni][v]);
        }
      }
    } else {
      unsigned short* dst = Vtb + (long)hb * HEADP * SEQL;
#pragma unroll
      for (int mi = 0; mi < 4; ++mi) {
        int s0 = m0 + wr * 64 + mi * 16 + g * 4;
#pragma unroll
        for (int ni = 0; ni < 2; ++ni) {
          int p = wc * 32 + ni * 16 + r;
          ushort4 pk;
          pk.x = f2bf(acc[mi][ni][0]); pk.y = f2bf(acc[mi][ni][1]);
          pk.z = f2bf(acc[mi][ni][2]); pk.w = f2bf(acc[mi][ni][3]);
          *reinterpret_cast<ushort4*>(dst + (long)p * SEQL + s0) = pk;
        }
      }
    }
  } else {
#pragma unroll
    for (int ni = 0; ni < 2; ++ni) {
      int c = n0 + wc * 32 + ni * 16 + r;
      float bv = bias[c];
#pragma unroll
      for (int mi = 0; mi < 4; ++mi) {
        int s0 = m0 + wr * 64 + mi * 16 + g * 4;
#pragma unroll
        for (int v = 0; v < 4; ++v)
          outf[(long)(s0 + v) * FINALD + c] = acc[mi][ni][v] + bv;
      }
    }
  }
}

// ---- fused sigmoid attention: single-pass, KVBLK=128 -------------------
// grid 512 (2 blocks/CU), block 256 (4 waves x 16 q-rows).
// 16 t-iterations of 128 (vs 32 of 64): halves the barrier-pair count.
// LDS: 2 x (K 16KB + V 16KB) dbuf + 4 x 4KB slabs = 80KB -> 2 blocks/CU.
// Swizzle idiom everywhere: physical_off = logical_off ^ ((row&7)<<4),
// applied on the pre-swizzled global source for staging (dest linear).
// Accumulation order over t identical to KVBLK=64 -> bit-identical output.
__global__ __launch_bounds__(256) void k_attn(
    const unsigned short* __restrict__ Qb,   // [H][S][P]
    const unsigned short* __restrict__ Kb,   // [H][S][P]
    const unsigned short* __restrict__ Vtb,  // [H][P][S]
    unsigned short* __restrict__ Ab) {       // [H][S][P] bf16
  __shared__ char lds[81920];
  int b = blockIdx.x;
  int xcd = b & 7, j = b >> 3;
  int h = (xcd << 1) | (j & 1);   // heads {2*xcd, 2*xcd+1} pinned to xcd
  int sblk = j >> 1;              // 0..31
  int lane = threadIdx.x & 63, wave = threadIdx.x >> 6;
  int r = lane & 15, g = lane >> 4;
  int q0 = sblk * 64 + wave * 16;
  const unsigned short* Qh = Qb + ((long)h * SEQL + q0) * HEADP;
  const unsigned short* Kh = Kb + (long)h * SEQL * HEADP;
  const unsigned short* Vh = Vtb + (long)h * HEADP * SEQL;

  bf16x8 qf0 = *reinterpret_cast<const bf16x8*>(Qh + (long)r * HEADP + g * 8);
  bf16x8 qf1 = *reinterpret_cast<const bf16x8*>(Qh + (long)r * HEADP + 32 + g * 8);

  f32x4 z4 = {0.f, 0.f, 0.f, 0.f};
  f32x4 oacc[4] = {z4, z4, z4, z4};
  char* slab = lds + 65536 + wave * 4096;    // 16 rows x 256 B per wave
  int swz = (r & 7) << 4;
  const float CLN = -0.02254211001389005f;   // -log2(e)/64

  // staging lane roles
  int sub8 = lane >> 3, chunk8 = lane & 7;      // K: 8 rows x 128B per gload
  int sub16 = lane >> 4, chunk16 = lane & 15;   // V: 4 rows x 256B per gload
  auto stage = [&](int buf, int t0) {
    char* kb = lds + buf * 32768 + wave * 4096;       // 32 K-rows per wave
    char* vb = lds + buf * 32768 + 16384 + wave * 4096;  // 16 V-rows per wave
#pragma unroll
    for (int jj = 0; jj < 4; ++jj) {
      int krow = wave * 32 + jj * 8 + sub8;
      gload16(Kh + (long)(t0 + krow) * HEADP + ((chunk8 ^ (krow & 7)) * 8),
              kb + jj * 1024);
      int vrow = wave * 16 + jj * 4 + sub16;
      gload16(Vh + (long)vrow * SEQL + t0 + ((chunk16 ^ (vrow & 7)) * 8),
              vb + jj * 1024);
    }
  };

  int cur = 0;
  stage(0, 0);                               // 8 loads in flight
  for (int t0 = 0; t0 < SEQL; t0 += 128) {
    __builtin_amdgcn_s_barrier();            // A: all done reading buf cur^1
    if (t0 + 128 < SEQL) {
      stage(cur ^ 1, t0 + 128);              // 8 more loads (16 outstanding)
      WAITV(8);                              // cur's loads landed
    } else {
      WAITV(0);
    }
    __builtin_amdgcn_s_barrier();            // B: everyone's cur loads landed
    __builtin_amdgcn_sched_barrier(0);

    const char* kb = lds + cur * 32768;
    const char* vb = kb + 16384;
    // S^T = K @ Q^T : lane holds S[t=tb*16+g*4+v][q=r], tb=0..7
    f32x4 s[8] = {z4, z4, z4, z4, z4, z4, z4, z4};
    __builtin_amdgcn_s_setprio(1);
#pragma unroll
    for (int tb = 0; tb < 8; ++tb) {
      const char* krow = kb + (tb * 16 + r) * 128;
      bf16x8 k0 = *reinterpret_cast<const bf16x8*>(krow + ((g ^ (r & 7)) * 16));
      bf16x8 k1 = *reinterpret_cast<const bf16x8*>(krow + (((4 + g) ^ (r & 7)) * 16));
      s[tb] = mfma16(k0, qf0, s[tb]);
      s[tb] = mfma16(k1, qf1, s[tb]);
    }
    __builtin_amdgcn_s_setprio(0);
    // sigmoid(S/64) -> bf16 -> per-wave slab (8B writes, swizzled 256B rows)
#pragma unroll
    for (int tb = 0; tb < 8; ++tb) {
      s16x4 pk;
#pragma unroll
      for (int v = 0; v < 4; ++v) {
        float e = __builtin_amdgcn_exp2f(s[tb][v] * CLN);
        pk[v] = (short)f2bf(__builtin_amdgcn_rcpf(1.0f + e));
      }
      *reinterpret_cast<s16x4*>(slab + r * 256 + ((tb * 32 + g * 8) ^ swz)) = pk;
    }
    // PV: 4 A-frags from slab, B-frags from V tile (256B rows)
    bf16x8 pa[4];
#pragma unroll
    for (int i = 0; i < 4; ++i)
      pa[i] = *reinterpret_cast<const bf16x8*>(slab + r * 256 + ((i * 64 + g * 16) ^ swz));
    __builtin_amdgcn_s_setprio(1);
#pragma unroll
    for (int nb = 0; nb < 4; ++nb) {
      const char* vrow = vb + (nb * 16 + r) * 256;
#pragma unroll
      for (int i = 0; i < 4; ++i) {
        bf16x8 vfr = *reinterpret_cast<const bf16x8*>(vrow + ((i * 64 + g * 16) ^ swz));
        oacc[nb] = mfma16(pa[i], vfr, oacc[nb]);
      }
    }
    __builtin_amdgcn_s_setprio(0);
    cur ^= 1;
  }
  unsigned short* Oh = Ab + ((long)h * SEQL + q0) * HEADP;
#pragma unroll
  for (int nb = 0; nb < 4; ++nb)
#pragma unroll
    for (int v = 0; v < 4; ++v)
      Oh[(g * 4 + v) * HEADP + nb * 16 + r] = f2bf(oacc[nb][v]);
}

// ---- launch -------------------------------------------------------------
extern "C" void kernel_launch(void* const* d_in, const int* in_sizes, int n_in,
                              void* d_out, int out_size, void* d_ws, size_t ws_size,
                              hipStream_t stream) {
  const float* x  = (const float*)d_in[0];
  const float* Qw = (const float*)d_in[1];
  const float* Kw = (const float*)d_in[2];
  const float* Vw = (const float*)d_in[3];
  const float* Wf = (const float*)d_in[4];
  const float* bf = (const float*)d_in[5];
  float* out = (float*)d_out;

  unsigned short* ws  = (unsigned short*)d_ws;
  unsigned short* xb  = ws;                // [2048][1024]       bytes [0,4M)
  unsigned short* Wt  = ws + 2097152;      // [3][16][64][1024]  bytes [4M,10M)
  unsigned short* WfT = ws + 5242880;      // [1024][1024]       bytes [10M,12M)
  unsigned short* Qb  = ws + 6291456;      // [16][2048][64]     bytes [12M,16M)
  unsigned short* Kb  = ws + 8388608;      //                    bytes [16M,20M)
  unsigned short* Vtb = ws + 10485760;     // [16][64][2048]     bytes [20M,24M)
  unsigned short* Ab  = ws + 12582912;     // [16][2048][64]     bytes [24M,28M)

  k_prep<<<dim3(16, 16, 5), 256, 0, stream>>>(Qw, Kw, Vw, Wf, x, Wt, WfT, xb);
  k_gemm<0><<<dim3(16, 48), 256, 0, stream>>>(xb, Wt, DMODEL, Qb, Kb, Vtb, nullptr, nullptr);
  k_attn<<<512, 256, 0, stream>>>(Qb, Kb, Vtb, Ab);
  k_gemm<1><<<dim3(16, 16), 256, 0, stream>>>(Ab, WfT, DMODEL, nullptr, nullptr, nullptr, bf, out);
}